// Round 2
// baseline (447.230 us; speedup 1.0000x reference)
//
#include <hip/hip_runtime.h>

typedef unsigned short u16;
typedef float  f32x4  __attribute__((ext_vector_type(4)));
typedef __bf16 bf16x8 __attribute__((ext_vector_type(8)));
typedef u16    u16x4  __attribute__((ext_vector_type(4)));

#define D_MODEL 1024
#define D_INNER 2048
#define B_SZ    2
#define SEQ     4096
#define MROWS   (B_SZ * SEQ)       // 8192
#define LTAPS   64                 // f[tau] ~ 0.4^tau -> negligible at 64

__device__ __forceinline__ u16 f2bf(float f) {
    unsigned u = __builtin_bit_cast(unsigned, f);
    unsigned r = u + 0x7FFFu + ((u >> 16) & 1u);
    return (u16)(r >> 16);
}
__device__ __forceinline__ float bf2f(u16 h) {
    unsigned u = ((unsigned)h) << 16;
    return __builtin_bit_cast(float, u);
}

typedef __attribute__((address_space(1))) void gv_t;
typedef __attribute__((address_space(3))) void lv_t;
__device__ __forceinline__ void glds16(const u16* g, u16* l) {
    __builtin_amdgcn_global_load_lds((gv_t*)g, (lv_t*)l, 16, 0, 0);
}

// ---------------------------------------------------------------------------
// Fused: fp32->bf16 convert of x (blocks 0..8191) + impulse-response setup
// (block 8192): fvec[tau] = Cp^T tanh(A)^tau Bp (+Dp at tau=0), f32.
// ---------------------------------------------------------------------------
__global__ __launch_bounds__(256) void setup_cvt_kernel(
    const float* __restrict__ in, u16* __restrict__ out,
    const float* __restrict__ A, const float* __restrict__ Bp,
    const float* __restrict__ Cp, const float* __restrict__ Dp,
    float* __restrict__ fvec)
{
    if (blockIdx.x == 8192) {
        const int tid = threadIdx.x;
        if (tid >= 64) return;
        const int i = tid & 15;            // lanes replicate in groups of 16
        float Atr[16];
        for (int j = 0; j < 16; j++) Atr[j] = tanhf(A[i * 16 + j]);
        float p = Bp[i];
        const float c  = Cp[i];
        const float d0 = Dp[0];
        for (int t = 0; t < LTAPS; t++) {
            float fv = c * p;
            fv += __shfl_xor(fv, 1); fv += __shfl_xor(fv, 2);
            fv += __shfl_xor(fv, 4); fv += __shfl_xor(fv, 8);
            if (tid == 0) fvec[t] = fv + (t == 0 ? d0 : 0.f);
            // p = Atr * p via 4 independent partial chains (shorter dep chain)
            float n0 = 0.f, n1 = 0.f, n2 = 0.f, n3 = 0.f;
            #pragma unroll
            for (int j = 0; j < 4; j++) {
                n0 = fmaf(Atr[j],      __shfl(p, j),      n0);
                n1 = fmaf(Atr[j + 4],  __shfl(p, j + 4),  n1);
                n2 = fmaf(Atr[j + 8],  __shfl(p, j + 8),  n2);
                n3 = fmaf(Atr[j + 12], __shfl(p, j + 12), n3);
            }
            p = (n0 + n1) + (n2 + n3);
        }
        return;
    }
    size_t i = ((size_t)blockIdx.x * 256 + threadIdx.x) * 4;
    f32x4 v = *(const f32x4*)(in + i);
    u16x4 o;
    o.x = f2bf(v.x); o.y = f2bf(v.y); o.z = f2bf(v.z); o.w = f2bf(v.w);
    *(u16x4*)(out + i) = o;
}

// ---------------------------------------------------------------------------
// fp32 [R][C] -> bf16 [C][R] transpose (weights)
// ---------------------------------------------------------------------------
__global__ __launch_bounds__(256) void transpose_cvt(
    const float* __restrict__ in, u16* __restrict__ out, int R, int C)
{
    __shared__ float tile[32][33];
    const int c0 = blockIdx.x * 32, r0 = blockIdx.y * 32;
    const int tx = threadIdx.x & 31, ty = threadIdx.x >> 5;   // 32 x 8
    for (int k = 0; k < 32; k += 8)
        tile[ty + k][tx] = in[(size_t)(r0 + ty + k) * C + c0 + tx];
    __syncthreads();
    for (int k = 0; k < 32; k += 8)
        out[(size_t)(c0 + ty + k) * R + r0 + tx] = f2bf(tile[tx][ty + k]);
}

// ---------------------------------------------------------------------------
// bt-GEMM, m97 structure: C[m][n] = sum_k A[m][k]*BT[n][k] + bias[n]
// BM=BN=128, BK=32, 256 thr (4 waves, 64x64 quadrant each), 16x16x32 bf16 MFMA
// XCD-aware tile remap: xcd = bid%8 owns an 8-m-tile strip (A strip stays
// resident in that XCD's 4 MiB L2; B swept once per strip).
// MODE 0: store bf16; MODE 1: store fp32
// ---------------------------------------------------------------------------
template <int MODE>
__global__ __launch_bounds__(256) void gemm_bt_kernel(
    const u16* __restrict__ A, const u16* __restrict__ BT,
    void* __restrict__ Cout, const float* __restrict__ bias,
    int M, int N, int K)
{
    __shared__ u16 As[128 * 32];
    __shared__ u16 Bs[128 * 32];
    const int tid = threadIdx.x, lane = tid & 63, wid = tid >> 6;
    // ---- XCD-locality remap (mTiles must be divisible by 8) ----
    const int nTiles = gridDim.x;
    const int bid = blockIdx.x + nTiles * blockIdx.y;   // HW dispatch order
    const int xcd = bid & 7;
    const int loc = bid >> 3;
    const int mt  = xcd * (gridDim.y >> 3) + (loc & 7); // loc%8 within strip
    const int nt  = loc >> 3;
    const int m0 = mt * 128, n0 = nt * 128;
    // staging: each wave covers 32 rows (2 instrs of 16 rows)
    const int sr = wid * 32 + (lane >> 2);
    const int sc = (lane & 3) * 8;
    const u16* ga = A  + (size_t)(m0 + sr) * K + sc;
    const u16* gb = BT + (size_t)(n0 + sr) * K + sc;
    u16* la = As + wid * 1024;
    u16* lb = Bs + wid * 1024;
    const int wm = (wid & 1) * 64, wn = (wid >> 1) * 64;
    const int fr = lane & 15, fq = lane >> 4;
    f32x4 acc[4][4] = {};
    for (int k0 = 0; k0 < K; k0 += 32) {
        glds16(ga + k0, la);
        glds16(ga + k0 + (size_t)16 * K, la + 512);
        glds16(gb + k0, lb);
        glds16(gb + k0 + (size_t)16 * K, lb + 512);
        asm volatile("s_waitcnt vmcnt(0)" ::: "memory");
        __syncthreads();
        bf16x8 af[4], bfr[4];
        for (int i = 0; i < 4; i++)
            af[i]  = *(const bf16x8*)(As + (wm + i * 16 + fr) * 32 + fq * 8);
        for (int i = 0; i < 4; i++)
            bfr[i] = *(const bf16x8*)(Bs + (wn + i * 16 + fr) * 32 + fq * 8);
        for (int mi = 0; mi < 4; mi++)
            for (int ni = 0; ni < 4; ni++)
                acc[mi][ni] = __builtin_amdgcn_mfma_f32_16x16x32_bf16(
                    af[mi], bfr[ni], acc[mi][ni], 0, 0, 0);
        __syncthreads();
    }
    for (int ni = 0; ni < 4; ni++) {
        const int col = n0 + wn + ni * 16 + fr;
        const float bv = bias[col];
        for (int mi = 0; mi < 4; mi++) {
            const int rowb = m0 + wm + mi * 16 + fq * 4;
            f32x4 v = acc[mi][ni];
            for (int r = 0; r < 4; r++) {
                float val = v[r] + bv;
                if constexpr (MODE == 0)
                    ((u16*)Cout)[(size_t)(rowb + r) * N + col] = f2bf(val);
                else
                    ((float*)Cout)[(size_t)(rowb + r) * N + col] = val;
            }
        }
    }
}

// ---------------------------------------------------------------------------
// Fused depthwise-conv(4) + 64-tap shared FIR + silu, all f32 in LDS/regs.
//   v[t][c] = cb[c] + sum_k cw[c][k] u[t-3+k][c]   (u[t<0]=0, v[t<0]=0)
//   y[t][c] = sum_{tau<64} f[tau] v[t-tau][c];  Y = silu(y)  (bf16)
// Block: 64 channels x 128 t-outputs; 256 thr = 64c x 4 t-groups.
// grid (32 c-tiles, 32 t-tiles, 2 batch) = 2048 blocks.
// ---------------------------------------------------------------------------
__global__ __launch_bounds__(256) void conv_fir_silu_kernel(
    const u16* __restrict__ u, const float* __restrict__ cw,
    const float* __restrict__ cb, const float* __restrict__ fvec,
    u16* __restrict__ Y)
{
    __shared__ float vbuf[191][65];     // rows s = t0-63 .. t0+127
    __shared__ float fs[LTAPS];
    const int tid = threadIdx.x;
    const int tx = tid & 63, ty = tid >> 6;
    const int c0 = blockIdx.x * 64, t0 = blockIdx.y * 128, b = blockIdx.z;
    const int cg = c0 + tx;
    if (tid < LTAPS) fs[tid] = fvec[tid];
    // ---- conv phase: fill vbuf ----
    const float w0 = cw[cg * 4 + 0], w1 = cw[cg * 4 + 1];
    const float w2 = cw[cg * 4 + 2], w3 = cw[cg * 4 + 3];
    const float cbv = cb[cg];
    const u16* ucol = u + (size_t)b * SEQ * D_INNER + cg;
    for (int r = ty; r < 191; r += 4) {
        const int s = t0 - 63 + r;
        float v = 0.f;
        if (s >= 0) {
            const int base = s - 3;
            float x0 = (base + 0 >= 0) ? bf2f(ucol[(size_t)(base + 0) * D_INNER]) : 0.f;
            float x1 = (base + 1 >= 0) ? bf2f(ucol[(size_t)(base + 1) * D_INNER]) : 0.f;
            float x2 = (base + 2 >= 0) ? bf2f(ucol[(size_t)(base + 2) * D_INNER]) : 0.f;
            float x3 = bf2f(ucol[(size_t)(base + 3) * D_INNER]);
            v = cbv + w0 * x0 + w1 * x1 + w2 * x2 + w3 * x3;
        }
        vbuf[r][tx] = v;
    }
    __syncthreads();
    // ---- FIR phase: thread -> 32 consecutive t outputs, register-blocked ----
    const int obase = ty * 32;                      // row offset in t-tile
    for (int ic = 0; ic < 2; ic++) {
        float acc[16];
        #pragma unroll
        for (int i = 0; i < 16; i++) acc[i] = 0.f;
        const int rb = obase + ic * 16 + 63;        // vbuf row = rb + i - tau
        for (int tb = 0; tb < 4; tb++) {
            const int T0 = tb * 16;
            float w[31];
            #pragma unroll
            for (int q = 0; q < 31; q++)
                w[q] = vbuf[rb - T0 - 15 + q][tx];
            #pragma unroll
            for (int ti = 0; ti < 16; ti++) {
                const float fv = fs[T0 + ti];
                #pragma unroll
                for (int i = 0; i < 16; i++)
                    acc[i] = fmaf(fv, w[15 + i - ti], acc[i]);
            }
        }
        const int trow = t0 + obase + ic * 16;
        #pragma unroll
        for (int i = 0; i < 16; i++) {
            float y = acc[i];
            float s = y / (1.f + __expf(-y));       // silu
            Y[((size_t)(b * SEQ + trow + i)) * D_INNER + cg] = f2bf(s);
        }
    }
}

// ---------------------------------------------------------------------------
extern "C" void kernel_launch(void* const* d_in, const int* in_sizes, int n_in,
                              void* d_out, int out_size, void* d_ws, size_t ws_size,
                              hipStream_t stream)
{
    const float* x    = (const float*)d_in[0];
    const float* Win  = (const float*)d_in[1];
    const float* bin  = (const float*)d_in[2];
    const float* cw   = (const float*)d_in[3];
    const float* cb   = (const float*)d_in[4];
    const float* A    = (const float*)d_in[5];
    const float* Bp   = (const float*)d_in[6];
    const float* Cp   = (const float*)d_in[7];
    const float* Dp   = (const float*)d_in[8];
    const float* Wout = (const float*)d_in[9];
    const float* bout = (const float*)d_in[10];
    float* out = (float*)d_out;

    char* ws = (char*)d_ws;
    u16*   xb    = (u16*)(ws);                      // 8192x1024 bf16   16 MB
    u16*   WinT  = (u16*)(ws + 16777216);           // 2048x1024 bf16    4 MB
    u16*   WoutT = (u16*)(ws + 20971520);           // 1024x2048 bf16    4 MB
    u16*   u     = (u16*)(ws + 25165824);           // 8192x2048 bf16   32 MB
    u16*   Y     = (u16*)(ws + 58720256);           // 8192x2048 bf16   32 MB
    float* fvec  = (float*)(ws + 92274688);         // 64 f32

    // x -> bf16 (+ impulse-response setup in the extra block)
    setup_cvt_kernel<<<8193, 256, 0, stream>>>(x, xb, A, Bp, Cp, Dp, fvec);
    transpose_cvt<<<dim3(64, 32), 256, 0, stream>>>(Win,  WinT,  1024, 2048);
    transpose_cvt<<<dim3(32, 64), 256, 0, stream>>>(Wout, WoutT, 2048, 1024);
    // u = x @ W_in + b_in  (bf16 out)
    gemm_bt_kernel<0><<<dim3(16, 64), 256, 0, stream>>>(xb, WinT, u, bin,
                                                        MROWS, D_INNER, D_MODEL);
    // fused conv + SSM-as-FIR + silu -> Y
    conv_fir_silu_kernel<<<dim3(32, 32, 2), 256, 0, stream>>>(u, cw, cb, fvec, Y);
    // out = Y @ W_out + b_out  (fp32 out)
    gemm_bt_kernel<1><<<dim3(8, 64), 256, 0, stream>>>(Y, WoutT, out, bout,
                                                       MROWS, D_MODEL, D_INNER);
}

// Round 3
// 260.084 us; speedup vs baseline: 1.7196x; 1.7196x over previous
//
#include <hip/hip_runtime.h>

typedef unsigned short u16;
typedef float  f32x4  __attribute__((ext_vector_type(4)));
typedef __bf16 bf16x8 __attribute__((ext_vector_type(8)));
typedef u16    u16x4  __attribute__((ext_vector_type(4)));

#define D_MODEL 1024
#define D_INNER 2048
#define B_SZ    2
#define SEQ     4096
#define MROWS   (B_SZ * SEQ)       // 8192
#define LTAPS   64                 // f[tau] ~ 0.4^tau -> negligible at 64
#define VROW    136                // VT row stride (u16): 272 B, 16B-aligned

__device__ __forceinline__ u16 f2bf(float f) {
    unsigned u = __builtin_bit_cast(unsigned, f);
    unsigned r = u + 0x7FFFu + ((u >> 16) & 1u);
    return (u16)(r >> 16);
}
__device__ __forceinline__ float bf2f(u16 h) {
    unsigned u = ((unsigned)h) << 16;
    return __builtin_bit_cast(float, u);
}

typedef __attribute__((address_space(1))) void gv_t;
typedef __attribute__((address_space(3))) void lv_t;
__device__ __forceinline__ void glds16(const u16* g, u16* l) {
    __builtin_amdgcn_global_load_lds((gv_t*)g, (lv_t*)l, 16, 0, 0);
}

// ---------------------------------------------------------------------------
// Prep (one launch): blocks [0,8192) cvt x->bf16; [8192,10240) transpose Win;
// [10240,12288) transpose Wout; block 12288 builds Amat64[64][128] bf16:
// Amat64[i][j] = f[64+i-j], f[tau] = Cp^T tanh(A)^tau Bp (+Dp at tau=0).
// ---------------------------------------------------------------------------
__device__ __forceinline__ void transpose_tile(
    const float* __restrict__ in, u16* __restrict__ out,
    int R, int C, int c0, int r0, int tid, float (*tile)[33])
{
    const int tx = tid & 31, ty = tid >> 5;   // 32 x 8
    for (int k = 0; k < 32; k += 8)
        tile[ty + k][tx] = in[(size_t)(r0 + ty + k) * C + c0 + tx];
    __syncthreads();
    for (int k = 0; k < 32; k += 8)
        out[(size_t)(c0 + ty + k) * R + r0 + tx] = f2bf(tile[tx][ty + k]);
}

__global__ __launch_bounds__(256) void prep_kernel(
    const float* __restrict__ x, u16* __restrict__ xb,
    const float* __restrict__ Win, u16* __restrict__ WinT,
    const float* __restrict__ Wout, u16* __restrict__ WoutT,
    const float* __restrict__ A, const float* __restrict__ Bp,
    const float* __restrict__ Cp, const float* __restrict__ Dp,
    u16* __restrict__ Amat64)
{
    __shared__ float tile[32][33];
    __shared__ float fs[LTAPS];
    const int bx = blockIdx.x, tid = threadIdx.x;
    if (bx < 8192) {
        size_t i = ((size_t)bx * 256 + tid) * 4;
        f32x4 v = *(const f32x4*)(x + i);
        u16x4 o;
        o.x = f2bf(v.x); o.y = f2bf(v.y); o.z = f2bf(v.z); o.w = f2bf(v.w);
        *(u16x4*)(xb + i) = o;
    } else if (bx < 10240) {
        const int flat = bx - 8192;                      // Win: 1024 x 2048
        transpose_tile(Win, WinT, 1024, 2048,
                       (flat & 63) * 32, (flat >> 6) * 32, tid, tile);
    } else if (bx < 12288) {
        const int flat = bx - 10240;                     // Wout: 2048 x 1024
        transpose_tile(Wout, WoutT, 2048, 1024,
                       (flat & 31) * 32, (flat >> 5) * 32, tid, tile);
    } else {
        if (tid < 64) {
            const int i = tid & 15;          // lanes replicate in groups of 16
            float Atr[16];
            for (int j = 0; j < 16; j++) Atr[j] = tanhf(A[i * 16 + j]);
            float p = Bp[i];
            const float c  = Cp[i];
            const float d0 = Dp[0];
            for (int t = 0; t < LTAPS; t++) {
                float fv = c * p;
                fv += __shfl_xor(fv, 1); fv += __shfl_xor(fv, 2);
                fv += __shfl_xor(fv, 4); fv += __shfl_xor(fv, 8);
                if (tid == 0) fs[t] = fv + (t == 0 ? d0 : 0.f);
                float n0 = 0.f, n1 = 0.f, n2 = 0.f, n3 = 0.f;
                #pragma unroll
                for (int j = 0; j < 4; j++) {
                    n0 = fmaf(Atr[j],      __shfl(p, j),      n0);
                    n1 = fmaf(Atr[j + 4],  __shfl(p, j + 4),  n1);
                    n2 = fmaf(Atr[j + 8],  __shfl(p, j + 8),  n2);
                    n3 = fmaf(Atr[j + 12], __shfl(p, j + 12), n3);
                }
                p = (n0 + n1) + (n2 + n3);
            }
        }
        __syncthreads();
        for (int idx = tid; idx < 64 * 128; idx += 256) {
            const int i = idx >> 7, j = idx & 127;
            const int tau = 64 + i - j;
            float v = (tau >= 0 && tau < LTAPS) ? fs[tau] : 0.f;
            Amat64[idx] = f2bf(v);
        }
    }
}

// ---------------------------------------------------------------------------
// bt-GEMM, m97 structure: C[m][n] = sum_k A[m][k]*BT[n][k] + bias[n]
// BM=BN=128, BK=32, 256 thr (4 waves, 64x64 quadrant each), 16x16x32 bf16 MFMA
// XCD-aware tile remap. MODE 0: store bf16; MODE 1: store fp32
// ---------------------------------------------------------------------------
template <int MODE>
__global__ __launch_bounds__(256) void gemm_bt_kernel(
    const u16* __restrict__ A, const u16* __restrict__ BT,
    void* __restrict__ Cout, const float* __restrict__ bias,
    int M, int N, int K)
{
    __shared__ u16 As[128 * 32];
    __shared__ u16 Bs[128 * 32];
    const int tid = threadIdx.x, lane = tid & 63, wid = tid >> 6;
    const int nTiles = gridDim.x;
    const int bid = blockIdx.x + nTiles * blockIdx.y;
    const int xcd = bid & 7;
    const int loc = bid >> 3;
    const int mt  = xcd * (gridDim.y >> 3) + (loc & 7);
    const int nt  = loc >> 3;
    const int m0 = mt * 128, n0 = nt * 128;
    const int sr = wid * 32 + (lane >> 2);
    const int sc = (lane & 3) * 8;
    const u16* ga = A  + (size_t)(m0 + sr) * K + sc;
    const u16* gb = BT + (size_t)(n0 + sr) * K + sc;
    u16* la = As + wid * 1024;
    u16* lb = Bs + wid * 1024;
    const int wm = (wid & 1) * 64, wn = (wid >> 1) * 64;
    const int fr = lane & 15, fq = lane >> 4;
    f32x4 acc[4][4] = {};
    for (int k0 = 0; k0 < K; k0 += 32) {
        glds16(ga + k0, la);
        glds16(ga + k0 + (size_t)16 * K, la + 512);
        glds16(gb + k0, lb);
        glds16(gb + k0 + (size_t)16 * K, lb + 512);
        asm volatile("s_waitcnt vmcnt(0)" ::: "memory");
        __syncthreads();
        bf16x8 af[4], bfr[4];
        for (int i = 0; i < 4; i++)
            af[i]  = *(const bf16x8*)(As + (wm + i * 16 + fr) * 32 + fq * 8);
        for (int i = 0; i < 4; i++)
            bfr[i] = *(const bf16x8*)(Bs + (wn + i * 16 + fr) * 32 + fq * 8);
        for (int mi = 0; mi < 4; mi++)
            for (int ni = 0; ni < 4; ni++)
                acc[mi][ni] = __builtin_amdgcn_mfma_f32_16x16x32_bf16(
                    af[mi], bfr[ni], acc[mi][ni], 0, 0, 0);
        __syncthreads();
    }
    for (int ni = 0; ni < 4; ni++) {
        const int col = n0 + wn + ni * 16 + fr;
        const float bv = bias[col];
        for (int mi = 0; mi < 4; mi++) {
            const int rowb = m0 + wm + mi * 16 + fq * 4;
            f32x4 v = acc[mi][ni];
            for (int r = 0; r < 4; r++) {
                float val = v[r] + bv;
                if constexpr (MODE == 0)
                    ((u16*)Cout)[(size_t)(rowb + r) * N + col] = f2bf(val);
                else
                    ((float*)Cout)[(size_t)(rowb + r) * N + col] = val;
            }
        }
    }
}

// ---------------------------------------------------------------------------
// Fused depthwise-conv(4) + 64-tap FIR (MFMA Toeplitz) + silu.
// Block: 64 t x 128 c, one batch. Conv fills VT[c][s] (bf16, s-window
// [t0-64, t0+64), row stride VROW=136). FIR: y[t0+m][c0+n] =
// sum_j Amat64[m][j] * VT[n][j]  (A-frags loaded straight from global).
// grid (16 c-tiles, 64 t-tiles, 2 batch) = 2048 blocks, 256 thr.
// ---------------------------------------------------------------------------
__global__ __launch_bounds__(256) void conv_fir_mfma_kernel(
    const u16* __restrict__ u, const float* __restrict__ cw,
    const float* __restrict__ cb, const u16* __restrict__ Amat64,
    u16* __restrict__ Y)
{
    __shared__ u16 VT[128 * VROW];          // 34816 B
    const int tid = threadIdx.x;
    const int c0 = blockIdx.x * 128, t0 = blockIdx.y * 64, b = blockIdx.z;
    // ---- conv phase: thread = one channel column, 64 consecutive s ----
    {
        const int tx = tid & 127, ty = tid >> 7;
        const int cg = c0 + tx;
        const float w0 = cw[cg * 4 + 0], w1 = cw[cg * 4 + 1];
        const float w2 = cw[cg * 4 + 2], w3 = cw[cg * 4 + 3];
        const float cbv = cb[cg];
        const u16* ucol = u + (size_t)b * SEQ * D_INNER + cg;
        const int s0 = t0 - 64 + ty * 64;
        u16* vrow = VT + tx * VROW + ty * 64;
        if (s0 + 63 < 0) {                       // whole half < 0 (t0==0, ty==0)
            const u16x4 z = {0, 0, 0, 0};
            #pragma unroll
            for (int j = 0; j < 16; j++) *(u16x4*)(vrow + j * 4) = z;
        } else {                                 // here s0 >= 0 always
            float xm3 = (s0 - 3 >= 0) ? bf2f(ucol[(size_t)(s0 - 3) * D_INNER]) : 0.f;
            float xm2 = (s0 - 2 >= 0) ? bf2f(ucol[(size_t)(s0 - 2) * D_INNER]) : 0.f;
            float xm1 = (s0 - 1 >= 0) ? bf2f(ucol[(size_t)(s0 - 1) * D_INNER]) : 0.f;
            #pragma unroll 4
            for (int j = 0; j < 16; j++) {
                const u16* p = ucol + (size_t)(s0 + j * 4) * D_INNER;
                float x0 = bf2f(p[0]);
                float x1 = bf2f(p[(size_t)D_INNER]);
                float x2 = bf2f(p[(size_t)2 * D_INNER]);
                float x3 = bf2f(p[(size_t)3 * D_INNER]);
                u16x4 o;
                o.x = f2bf(cbv + w0 * xm3 + w1 * xm2 + w2 * xm1 + w3 * x0);
                o.y = f2bf(cbv + w0 * xm2 + w1 * xm1 + w2 * x0  + w3 * x1);
                o.z = f2bf(cbv + w0 * xm1 + w1 * x0  + w2 * x1  + w3 * x2);
                o.w = f2bf(cbv + w0 * x0  + w1 * x1  + w2 * x2  + w3 * x3);
                *(u16x4*)(vrow + j * 4) = o;
                xm3 = x1; xm2 = x2; xm1 = x3;
            }
        }
    }
    __syncthreads();
    // ---- FIR phase: 4 waves, each 32t x 64c quadrant ----
    const int lane = tid & 63, wid = tid >> 6;
    const int wm = (wid & 1) * 32, wn = (wid >> 1) * 64;
    const int fr = lane & 15, fq = lane >> 4;
    f32x4 acc[2][4] = {};
    #pragma unroll
    for (int kq = 0; kq < 4; kq++) {
        const int k0 = kq * 32;
        bf16x8 af[2], bfr[4];
        #pragma unroll
        for (int mi = 0; mi < 2; mi++)
            af[mi] = *(const bf16x8*)(Amat64 + (wm + mi * 16 + fr) * 128 + k0 + fq * 8);
        #pragma unroll
        for (int ni = 0; ni < 4; ni++)
            bfr[ni] = *(const bf16x8*)(VT + (wn + ni * 16 + fr) * VROW + k0 + fq * 8);
        #pragma unroll
        for (int mi = 0; mi < 2; mi++)
            #pragma unroll
            for (int ni = 0; ni < 4; ni++)
                acc[mi][ni] = __builtin_amdgcn_mfma_f32_16x16x32_bf16(
                    af[mi], bfr[ni], acc[mi][ni], 0, 0, 0);
    }
    #pragma unroll
    for (int ni = 0; ni < 4; ni++) {
        const int col = c0 + wn + ni * 16 + fr;
        #pragma unroll
        for (int mi = 0; mi < 2; mi++) {
            const int rowb = t0 + wm + mi * 16 + fq * 4;
            f32x4 v = acc[mi][ni];
            #pragma unroll
            for (int r = 0; r < 4; r++) {
                float y = v[r];
                float s = y / (1.f + __expf(-y));          // silu
                Y[((size_t)(b * SEQ + rowb + r)) * D_INNER + col] = f2bf(s);
            }
        }
    }
}

// ---------------------------------------------------------------------------
extern "C" void kernel_launch(void* const* d_in, const int* in_sizes, int n_in,
                              void* d_out, int out_size, void* d_ws, size_t ws_size,
                              hipStream_t stream)
{
    const float* x    = (const float*)d_in[0];
    const float* Win  = (const float*)d_in[1];
    const float* bin  = (const float*)d_in[2];
    const float* cw   = (const float*)d_in[3];
    const float* cb   = (const float*)d_in[4];
    const float* A    = (const float*)d_in[5];
    const float* Bp   = (const float*)d_in[6];
    const float* Cp   = (const float*)d_in[7];
    const float* Dp   = (const float*)d_in[8];
    const float* Wout = (const float*)d_in[9];
    const float* bout = (const float*)d_in[10];
    float* out = (float*)d_out;

    char* ws = (char*)d_ws;
    u16* xb     = (u16*)(ws);                      // 8192x1024 bf16   16 MB
    u16* WinT   = (u16*)(ws + 16777216);           // 2048x1024 bf16    4 MB
    u16* WoutT  = (u16*)(ws + 20971520);           // 1024x2048 bf16    4 MB
    u16* u      = (u16*)(ws + 25165824);           // 8192x2048 bf16   32 MB
    u16* Y      = (u16*)(ws + 58720256);           // 8192x2048 bf16   32 MB
    u16* Amat64 = (u16*)(ws + 92274688);           // 64x128 bf16      16 KB

    // all conversions/transposes/setup in one launch
    prep_kernel<<<12289, 256, 0, stream>>>(x, xb, Win, WinT, Wout, WoutT,
                                           A, Bp, Cp, Dp, Amat64);
    // u = x @ W_in + b_in  (bf16 out)
    gemm_bt_kernel<0><<<dim3(16, 64), 256, 0, stream>>>(xb, WinT, u, bin,
                                                        MROWS, D_INNER, D_MODEL);
    // fused conv + SSM-as-FIR (MFMA Toeplitz) + silu -> Y
    conv_fir_mfma_kernel<<<dim3(16, 64, 2), 256, 0, stream>>>(u, cw, cb, Amat64, Y);
    // out = Y @ W_out + b_out  (fp32 out)
    gemm_bt_kernel<1><<<dim3(8, 64), 256, 0, stream>>>(Y, WoutT, out, bout,
                                                       MROWS, D_MODEL, D_INNER);
}